// Round 6
// baseline (3104.621 us; speedup 1.0000x reference)
//
#include <hip/hip_runtime.h>
#include <hip/hip_bf16.h>
#include <stdint.h>

#define T_STEPS 512
#define BATCH   256
#define DIN     85
#define HDIM    512
#define NOUT    33

#define GRP   16     // blocks per group
#define BBLK  16     // batch rows per group
#define HS    32     // H columns per block
#define LDA   1040   // bytes per padded row of h A-tile (520 elems, 16B-aligned)
#define LDX   208    // bytes per padded row of x A-tile (104 elems)
#define RING  8      // replica ring depth (drift within a group is <=1 step)

// bf16 NaN|NaN pair — unreachable as packed h output (|h|<1, finite),
// used as the "not yet written" sentinel so the data is its own flag.
#define SENT  0x7FC07FC0u

typedef __attribute__((ext_vector_type(8))) short s8v;       // 8 x bf16
typedef __attribute__((ext_vector_type(4))) float f4v;       // MFMA accumulator
typedef __attribute__((ext_vector_type(4))) uint32_t u32x4;  // 16B chunk

__device__ __forceinline__ uint16_t f2bf(float f) {
    uint32_t x = __builtin_bit_cast(uint32_t, f);
    uint32_t r = (x + 0x7fffu + ((x >> 16) & 1u)) >> 16;
    return (uint16_t)r;
}
__device__ __forceinline__ float sigm(float v) {
    v = fminf(fmaxf(v, -30.f), 30.f);
    return 1.f / (1.f + __expf(-v));
}
__device__ __forceinline__ float tanh_f(float v) {
    v = fminf(fmaxf(v, -15.f), 15.f);
    float e = __expf(2.f * v);
    return (e - 1.f) / (e + 1.f);
}
__device__ __forceinline__ s8v cvt8(const float* p) {
    s8v v;
#pragma unroll
    for (int j = 0; j < 8; ++j) v[j] = (short)f2bf(p[j]);
    return v;
}

// plain store: write-through L1 -> lands in the producing XCD's L2 (fast path)
__device__ __forceinline__ void store_plain(uint32_t* p, uint32_t v) {
    asm volatile("global_store_dword %0, %1, off" :: "v"(p), "v"(v) : "memory");
}
// sc0 16B load: bypass L1, served by the XCD-local L2 (fast path probe)
__device__ __forceinline__ u32x4 load4_sc0(const uint32_t* p) {
    u32x4 v;
    asm volatile("global_load_dwordx4 %0, %1, off sc0\n\t"
                 "s_waitcnt vmcnt(0)"
                 : "=&v"(v) : "v"(p) : "memory");
    return v;
}
__device__ __forceinline__ void load16_sc0(const uint32_t* p0, const uint32_t* p1,
                                           const uint32_t* p2, const uint32_t* p3,
                                           u32x4& a, u32x4& b, u32x4& c, u32x4& d) {
    asm volatile("global_load_dwordx4 %0, %4, off sc0\n\t"
                 "global_load_dwordx4 %1, %5, off sc0\n\t"
                 "global_load_dwordx4 %2, %6, off sc0\n\t"
                 "global_load_dwordx4 %3, %7, off sc0\n\t"
                 "s_waitcnt vmcnt(0)"
                 : "=&v"(a), "=&v"(b), "=&v"(c), "=&v"(d)
                 : "v"(p0), "v"(p1), "v"(p2), "v"(p3)
                 : "memory");
}
// replica (agent-coherent, round-4-proven path) chunk load
__device__ __forceinline__ u32x4 load4_rep(const uint32_t* p) {
    u32x4 v;
#pragma unroll
    for (int d = 0; d < 4; ++d)
        v[d] = __hip_atomic_load(p + d, __ATOMIC_RELAXED, __HIP_MEMORY_SCOPE_AGENT);
    return v;
}
__device__ __forceinline__ uint32_t has_sent(const u32x4& v) {
    return (uint32_t)(v[0] == SENT) | (uint32_t)(v[1] == SENT) |
           (uint32_t)(v[2] == SENT) | (uint32_t)(v[3] == SENT);
}

// Fill primary hbuf (513 slots) + replica ring (8 slots) with the sentinel.
__global__ __launch_bounds__(256) void lstm_init(uint32_t* __restrict__ hbuf,
                                                 uint32_t* __restrict__ rep)
{
    u32x4 s; s[0] = SENT; s[1] = SENT; s[2] = SENT; s[3] = SENT;
    const size_t stride = (size_t)gridDim.x * 256;
    const size_t i0 = (size_t)blockIdx.x * 256 + threadIdx.x;
    const size_t n4h = (size_t)(T_STEPS + 1) * (BATCH * HDIM / 2) / 4;
    u32x4* ph = (u32x4*)hbuf;
    for (size_t i = i0; i < n4h; i += stride) ph[i] = s;
    const size_t n4r = (size_t)RING * (BATCH * HDIM / 2) / 4;
    u32x4* pr = (u32x4*)rep;
    for (size_t i = i0; i < n4r; i += stride) pr[i] = s;
}

// Persistent recurrence. 256 blocks = 16 groups x 16 members, STATIC mapping
// grp = bid&15, mem = bid>>4  -> all members of a group share bid%8, so under
// the CP's round-robin XCD assignment a group is same-XCD (fast path). No
// correctness dependence on placement: h is published twice —
//   primary: plain store into local L2, polled with sc0 loads (fast),
//   replica: relaxed agent store (MALL), polled as per-chunk fallback after
//            8 failed primary rounds (correct under ANY placement).
// Sentinel protocol on both; replica is an 8-slot ring re-sentineled by mem 0.
__global__ __launch_bounds__(256, 1) void lstm_rec(
    const float* __restrict__ x,
    const float* __restrict__ Wxi, const float* __restrict__ Wxf,
    const float* __restrict__ Wxo, const float* __restrict__ Wxc,
    const float* __restrict__ Whi, const float* __restrict__ bhi,
    const float* __restrict__ Whf, const float* __restrict__ bhf,
    const float* __restrict__ Who, const float* __restrict__ bho,
    const float* __restrict__ Whc, const float* __restrict__ bhc,
    uint16_t* __restrict__ hbuf,      // [T_STEPS+1][BATCH][HDIM] bf16 (scratch)
    uint32_t* __restrict__ rep)       // [RING][BATCH][HDIM/2] packed replica
{
    __shared__ __align__(16) uint8_t hA[16 * LDA];   // 16.6 KB
    __shared__ __align__(16) uint8_t xA[16 * LDX];   // 3.3 KB
    __shared__ float gbuf[4 * 16 * 33];              // 8.4 KB

    const int tid = threadIdx.x;
    const int bid = blockIdx.x;
    const int grp = bid & 15;
    const int mem = bid >> 4;
    const int b0  = grp * BBLK;
    const int hs  = mem * HS;

    const int wave  = tid >> 6;       // gate: 0=i 1=f 2=o 3=c
    const int lane  = tid & 63;
    const int col16 = lane & 15;
    const int quad  = lane >> 4;

    const float* Wh  = (wave == 0) ? Whi : (wave == 1) ? Whf : (wave == 2) ? Who : Whc;
    const float* Wxp = (wave == 0) ? Wxi : (wave == 1) ? Wxf : (wave == 2) ? Wxo : Wxc;

    // ---- B-fragments (weights) into registers, once (fp32 -> bf16 RNE) ----
    s8v bh[2][16];
#pragma unroll
    for (int nt = 0; nt < 2; ++nt) {
        const float* rowp = Wh + (size_t)(hs + nt * 16 + col16) * HDIM;
#pragma unroll
        for (int kt = 0; kt < 16; ++kt)
            bh[nt][kt] = cvt8(rowp + kt * 32 + quad * 8);
    }
    s8v bx[2][3];
#pragma unroll
    for (int nt = 0; nt < 2; ++nt) {
        const float* rowp = Wxp + (size_t)(hs + nt * 16 + col16) * DIN;
#pragma unroll
        for (int kt = 0; kt < 3; ++kt) {
            s8v v;
#pragma unroll
            for (int j = 0; j < 8; ++j) {
                int k = kt * 32 + quad * 8 + j;
                v[j] = (k < DIN) ? (short)f2bf(rowp[k]) : (short)0;
            }
            bx[nt][kt] = v;
        }
    }

    // ---- pointwise mapping: thread -> (row r, cols c0,c0+1) of 16x32 slice ----
    const int r  = tid >> 4;
    const int c0 = (tid & 15) * 2;
    const float bi0 = bhi[hs + c0], bi1 = bhi[hs + c0 + 1];
    const float bf0 = bhf[hs + c0], bf1 = bhf[hs + c0 + 1];
    const float bo0 = bho[hs + c0], bo1 = bho[hs + c0 + 1];
    const float bc0 = bhc[hs + c0], bc1 = bhc[hs + c0 + 1];
    float C0 = 0.f, C1 = 0.f;

    uint32_t* hbuf32 = (uint32_t*)hbuf;
    const size_t hslot = ((size_t)(b0 + r) * HDIM + hs + c0) >> 1;  // abs u32 idx in a slot

    // ---- refill chunk mapping: chunk c = tid + 256q -> row c>>6, 16B col c&63
    const int rrow[4] = { tid >> 6, (tid + 256) >> 6, (tid + 512) >> 6, (tid + 768) >> 6 };
    const int rc8     = tid & 63;

    // ---- x prefetch (fp32 registers) ----
    float xreg[6];
    auto load_x = [&](int t) {
#pragma unroll
        for (int j = 0; j < 6; ++j) {
            int v = tid + j * 256;
            int row = v / 96, k = v % 96;
            xreg[j] = (k < DIN) ? x[(size_t)(t * BATCH + b0 + row) * DIN + k] : 0.f;
        }
    };
    auto store_x = [&]() {   // waits on the x loads (overlaps h propagation)
#pragma unroll
        for (int j = 0; j < 6; ++j) {
            int v = tid + j * 256;
            int row = v / 96, k = v % 96;
            *(uint16_t*)(xA + row * LDX + k * 2) = f2bf(xreg[j]);
        }
    };

    // init: h(0)=0 in LDS, stage x(0)
    load_x(0);
    for (int j = tid; j < 16 * LDA / 16; j += 256) {
        s8v z;
#pragma unroll
        for (int q = 0; q < 8; ++q) z[q] = 0;
        ((s8v*)hA)[j] = z;
    }
    store_x();
    __syncthreads();

    for (int t = 0; t < T_STEPS; ++t) {
        if (t < T_STEPS - 1) load_x(t + 1);   // flies through GEMM + pointwise

        // ---- GEMM: pre-activations for this wave's gate, 16 rows x 32 cols ----
        f4v acc0 = {0.f, 0.f, 0.f, 0.f}, acc1 = {0.f, 0.f, 0.f, 0.f};
#pragma unroll
        for (int kt = 0; kt < 16; ++kt) {
            s8v a = *(const s8v*)(hA + col16 * LDA + kt * 64 + quad * 16);
            acc0 = __builtin_amdgcn_mfma_f32_16x16x32_bf16(a, bh[0][kt], acc0, 0, 0, 0);
            acc1 = __builtin_amdgcn_mfma_f32_16x16x32_bf16(a, bh[1][kt], acc1, 0, 0, 0);
        }
#pragma unroll
        for (int kt = 0; kt < 3; ++kt) {
            s8v a = *(const s8v*)(xA + col16 * LDX + kt * 64 + quad * 16);
            acc0 = __builtin_amdgcn_mfma_f32_16x16x32_bf16(a, bx[0][kt], acc0, 0, 0, 0);
            acc1 = __builtin_amdgcn_mfma_f32_16x16x32_bf16(a, bx[1][kt], acc1, 0, 0, 0);
        }
#pragma unroll
        for (int rr = 0; rr < 4; ++rr) {
            int b = quad * 4 + rr;
            gbuf[(wave * 16 + b) * 33 + col16]      = acc0[rr];
            gbuf[(wave * 16 + b) * 33 + 16 + col16] = acc1[rr];
        }
        __syncthreads();   // gbuf complete; hA/xA reads of this step done

        // ---- pointwise ----
        float pi0 = gbuf[(0 * 16 + r) * 33 + c0] + bi0;
        float pi1 = gbuf[(0 * 16 + r) * 33 + c0 + 1] + bi1;
        float pf0 = gbuf[(1 * 16 + r) * 33 + c0] + bf0;
        float pf1 = gbuf[(1 * 16 + r) * 33 + c0 + 1] + bf1;
        float po0 = gbuf[(2 * 16 + r) * 33 + c0] + bo0;
        float po1 = gbuf[(2 * 16 + r) * 33 + c0 + 1] + bo1;
        float pc0 = gbuf[(3 * 16 + r) * 33 + c0] + bc0;
        float pc1 = gbuf[(3 * 16 + r) * 33 + c0 + 1] + bc1;

        float I0 = sigm(pi0), F0 = sigm(pf0), O0 = sigm(po0), G0 = tanh_f(pc0);
        float I1 = sigm(pi1), F1 = sigm(pf1), O1 = sigm(po1), G1 = tanh_f(pc1);
        C0 = F0 * C0 + I0 * G0;
        C1 = F1 * C1 + I1 * G1;
        float h0 = O0 * tanh_f(C0);
        float h1 = O1 * tanh_f(C1);

        uint32_t packed = (uint32_t)f2bf(h0) | ((uint32_t)f2bf(h1) << 16);
        // primary: plain store -> local L2 (fast path; flushed at kernel end
        // for lstm_out). replica: agent store -> MALL (fallback path).
        store_plain(&hbuf32[(size_t)(t + 1) * (BATCH * HDIM / 2) + hslot], packed);
        __hip_atomic_store(&rep[(size_t)((t + 1) & (RING - 1)) * (BATCH * HDIM / 2) + hslot],
                           packed, __ATOMIC_RELAXED, __HIP_MEMORY_SCOPE_AGENT);

        if (t == T_STEPS - 1) break;

        store_x();   // drains x loads so polls' vmcnt(0) is poll-only

        // ---- refill h(t+1): primary sc0 poll, per-chunk replica fallback ----
        const uint32_t* src = hbuf32 + (size_t)(t + 1) * (BATCH * HDIM / 2)
                                     + (size_t)b0 * (HDIM / 2);
        const uint32_t* rsc = rep + (size_t)((t + 1) & (RING - 1)) * (BATCH * HDIM / 2)
                                  + (size_t)b0 * (HDIM / 2);
        const uint32_t* p0 = src + (size_t)rrow[0] * (HDIM / 2) + rc8 * 4;
        const uint32_t* p1 = src + (size_t)rrow[1] * (HDIM / 2) + rc8 * 4;
        const uint32_t* p2 = src + (size_t)rrow[2] * (HDIM / 2) + rc8 * 4;
        const uint32_t* p3 = src + (size_t)rrow[3] * (HDIM / 2) + rc8 * 4;
        const uint32_t* q0 = rsc + (size_t)rrow[0] * (HDIM / 2) + rc8 * 4;
        const uint32_t* q1 = rsc + (size_t)rrow[1] * (HDIM / 2) + rc8 * 4;
        const uint32_t* q2 = rsc + (size_t)rrow[2] * (HDIM / 2) + rc8 * 4;
        const uint32_t* q3 = rsc + (size_t)rrow[3] * (HDIM / 2) + rc8 * 4;

        u32x4 v0, v1, v2, v3;
        load16_sc0(p0, p1, p2, p3, v0, v1, v2, v3);
        int round = 0;
        while (has_sent(v0) | has_sent(v1) | has_sent(v2) | has_sent(v3)) {
            if (round >= 3) __builtin_amdgcn_s_sleep(1);
            if (round < 8) {           // same-XCD fast path (~L2 RT per round)
                if (has_sent(v0)) v0 = load4_sc0(p0);
                if (has_sent(v1)) v1 = load4_sc0(p1);
                if (has_sent(v2)) v2 = load4_sc0(p2);
                if (has_sent(v3)) v3 = load4_sc0(p3);
            } else {                   // coherent fallback (any placement)
                if (has_sent(v0)) v0 = load4_rep(q0);
                if (has_sent(v1)) v1 = load4_rep(q1);
                if (has_sent(v2)) v2 = load4_rep(q2);
                if (has_sent(v3)) v3 = load4_rep(q3);
            }
            if (++round > 300000) break;   // never hang
        }
        *(u32x4*)(hA + rrow[0] * LDA + rc8 * 16) = v0;
        *(u32x4*)(hA + rrow[1] * LDA + rc8 * 16) = v1;
        *(u32x4*)(hA + rrow[2] * LDA + rc8 * 16) = v2;
        *(u32x4*)(hA + rrow[3] * LDA + rc8 * 16) = v3;

        // re-sentinel the ring slot consumed 2 steps ago (quiescent: group
        // drift <=1 step; slot reused 7 steps from now). One member suffices.
        if (mem == 0 && t >= 1) {
            uint32_t* rz = rep + (size_t)((t - 1) & (RING - 1)) * (BATCH * HDIM / 2)
                               + (size_t)b0 * (HDIM / 2);
#pragma unroll
            for (int q = 0; q < 4; ++q) {
                uint32_t* pz = rz + (size_t)rrow[q] * (HDIM / 2) + rc8 * 4;
#pragma unroll
                for (int d = 0; d < 4; ++d)
                    __hip_atomic_store(pz + d, SENT, __ATOMIC_RELAXED,
                                       __HIP_MEMORY_SCOPE_AGENT);
            }
        }

        __syncthreads();   // hA/xA staged for next step
    }
}

// Readout: out[t,b,:] = h[t+1] @ Wro^T + bro.  MFMA, N padded 33->48. fp32 out.
__global__ __launch_bounds__(256, 1) void lstm_out(
    const uint16_t* __restrict__ hbuf,
    const float* __restrict__ Wro, const float* __restrict__ bro,
    float* __restrict__ out)
{
    __shared__ __align__(16) uint8_t hT[64 * LDA];   // 66.6 KB

    const int tid   = threadIdx.x;
    const int bid   = blockIdx.x;
    const int wave  = tid >> 6;
    const int lane  = tid & 63;
    const int col16 = lane & 15;
    const int quad  = lane >> 4;

    s8v bw[3][16];
    float bias[3];
#pragma unroll
    for (int nt = 0; nt < 3; ++nt) {
        int o = nt * 16 + col16;
        bias[nt] = (o < NOUT) ? bro[o] : 0.f;
#pragma unroll
        for (int kt = 0; kt < 16; ++kt) {
            if (o < NOUT) {
                bw[nt][kt] = cvt8(Wro + (size_t)o * HDIM + kt * 32 + quad * 8);
            } else {
                s8v z;
#pragma unroll
                for (int q = 0; q < 8; ++q) z[q] = 0;
                bw[nt][kt] = z;
            }
        }
    }

    const uint16_t* hsrc = hbuf + (size_t)BATCH * HDIM;  // skip t=0 slot

    for (int sub = 0; sub < 8; ++sub) {
        size_t row0 = (size_t)bid * 512 + (size_t)sub * 64;
#pragma unroll
        for (int j = 0; j < 16; ++j) {
            int v = tid + j * 256;
            int row = v >> 6, c8 = v & 63;
            s8v val = *(const s8v*)(hsrc + (row0 + row) * HDIM + c8 * 8);
            *(s8v*)(hT + row * LDA + c8 * 16) = val;
        }
        __syncthreads();

        f4v acc[3];
#pragma unroll
        for (int nt = 0; nt < 3; ++nt) acc[nt] = (f4v){0.f, 0.f, 0.f, 0.f};
#pragma unroll
        for (int kt = 0; kt < 16; ++kt) {
            s8v a = *(const s8v*)(hT + (wave * 16 + col16) * LDA + kt * 64 + quad * 16);
#pragma unroll
            for (int nt = 0; nt < 3; ++nt)
                acc[nt] = __builtin_amdgcn_mfma_f32_16x16x32_bf16(a, bw[nt][kt], acc[nt], 0, 0, 0);
        }
#pragma unroll
        for (int nt = 0; nt < 3; ++nt) {
            int o = nt * 16 + col16;
            if (o < NOUT) {
#pragma unroll
                for (int rr = 0; rr < 4; ++rr) {
                    size_t rg = row0 + (size_t)wave * 16 + quad * 4 + rr;
                    out[rg * NOUT + o] = acc[nt][rr] + bias[nt];
                }
            }
        }
        __syncthreads();
    }
}

extern "C" void kernel_launch(void* const* d_in, const int* in_sizes, int n_in,
                              void* d_out, int out_size, void* d_ws, size_t ws_size,
                              hipStream_t stream)
{
    const float* x   = (const float*)d_in[0];
    const float* Wxi = (const float*)d_in[1];
    const float* Wxf = (const float*)d_in[2];
    const float* Wxo = (const float*)d_in[3];
    const float* Wxc = (const float*)d_in[4];
    const float* Whi = (const float*)d_in[5];
    const float* bhi = (const float*)d_in[6];
    const float* Whf = (const float*)d_in[7];
    const float* bhf = (const float*)d_in[8];
    const float* Who = (const float*)d_in[9];
    const float* bho = (const float*)d_in[10];
    const float* Whc = (const float*)d_in[11];
    const float* bhc = (const float*)d_in[12];
    const float* Wro = (const float*)d_in[13];
    const float* bro = (const float*)d_in[14];
    float* out = (float*)d_out;

    uint8_t* ws = (uint8_t*)d_ws;
    uint32_t* rep  = (uint32_t*)ws;                       // RING slots: 8*256KB = 2 MB
    uint16_t* hbuf = (uint16_t*)(ws + (RING + 1) * (size_t)(BATCH * HDIM / 2) * 4);

    lstm_init<<<2048, 256, 0, stream>>>((uint32_t*)hbuf, rep);
    lstm_rec<<<256, 256, 0, stream>>>(x, Wxi, Wxf, Wxo, Wxc,
                                      Whi, bhi, Whf, bhf, Who, bho, Whc, bhc,
                                      hbuf, rep);
    lstm_out<<<256, 256, 0, stream>>>(hbuf, Wro, bro, out);
}

// Round 7
// 2047.282 us; speedup vs baseline: 1.5165x; 1.5165x over previous
//
#include <hip/hip_runtime.h>
#include <hip/hip_bf16.h>
#include <stdint.h>

#define T_STEPS 512
#define BATCH   256
#define DIN     85
#define HDIM    512
#define NOUT    33

#define GRP   16     // blocks per group
#define BBLK  16     // batch rows per group
#define HS    32     // H columns per block
#define LDA   1040   // bytes per padded row of h A-tile (520 elems, 16B-aligned)
#define LDX   208    // bytes per padded row of x A-tile (104 elems)

// bf16 NaN|NaN pair — unreachable as packed h output (|h|<1, finite),
// used as the "not yet written" sentinel so the data is its own flag.
#define SENT  0x7FC07FC0u

typedef __attribute__((ext_vector_type(8))) short s8v;       // 8 x bf16
typedef __attribute__((ext_vector_type(4))) float f4v;       // MFMA accumulator
typedef __attribute__((ext_vector_type(4))) uint32_t u32x4;  // 16B chunk

__device__ __forceinline__ uint16_t f2bf(float f) {
    uint32_t x = __builtin_bit_cast(uint32_t, f);
    uint32_t r = (x + 0x7fffu + ((x >> 16) & 1u)) >> 16;
    return (uint16_t)r;
}
__device__ __forceinline__ float sigm(float v) {
    v = fminf(fmaxf(v, -30.f), 30.f);
    return 1.f / (1.f + __expf(-v));
}
__device__ __forceinline__ float tanh_f(float v) {
    v = fminf(fmaxf(v, -15.f), 15.f);
    float e = __expf(2.f * v);
    return (e - 1.f) / (e + 1.f);
}
__device__ __forceinline__ s8v cvt8(const float* p) {
    s8v v;
#pragma unroll
    for (int j = 0; j < 8; ++j) v[j] = (short)f2bf(p[j]);
    return v;
}

// agent-coherent 16B load (sc0 sc1 = bypass L1+L2, served at coherence point),
// same semantics as 4x relaxed agent atomic_load but 1 MALL transaction.
__device__ __forceinline__ u32x4 load4_coh(const uint32_t* p) {
    u32x4 v;
    asm volatile("global_load_dwordx4 %0, %1, off sc0 sc1\n\t"
                 "s_waitcnt vmcnt(0)"
                 : "=&v"(v) : "v"(p) : "memory");
    return v;
}
__device__ __forceinline__ void load16_coh(const uint32_t* p0, const uint32_t* p1,
                                           const uint32_t* p2, const uint32_t* p3,
                                           u32x4& a, u32x4& b, u32x4& c, u32x4& d) {
    asm volatile("global_load_dwordx4 %0, %4, off sc0 sc1\n\t"
                 "global_load_dwordx4 %1, %5, off sc0 sc1\n\t"
                 "global_load_dwordx4 %2, %6, off sc0 sc1\n\t"
                 "global_load_dwordx4 %3, %7, off sc0 sc1\n\t"
                 "s_waitcnt vmcnt(0)"
                 : "=&v"(a), "=&v"(b), "=&v"(c), "=&v"(d)
                 : "v"(p0), "v"(p1), "v"(p2), "v"(p3)
                 : "memory");
}
__device__ __forceinline__ uint32_t has_sent(const u32x4& v) {
    return (uint32_t)(v[0] == SENT) | (uint32_t)(v[1] == SENT) |
           (uint32_t)(v[2] == SENT) | (uint32_t)(v[3] == SENT);
}

// Fill hbuf with the sentinel before the recurrence.
__global__ __launch_bounds__(256) void lstm_init(uint32_t* __restrict__ hbuf)
{
    const size_t n4 = (size_t)(T_STEPS + 1) * BATCH * HDIM / 2 / 4;
    u32x4 s; s[0] = SENT; s[1] = SENT; s[2] = SENT; s[3] = SENT;
    u32x4* p = (u32x4*)hbuf;
    for (size_t i = (size_t)blockIdx.x * 256 + threadIdx.x; i < n4;
         i += (size_t)gridDim.x * 256)
        p[i] = s;
}

// Persistent recurrence kernel. 256 blocks = 16 groups x 16 members.
// Group owns 16 batch rows; member owns 32 H columns (x4 gates, one per wave).
// Weights live in registers as MFMA B-fragments for the whole kernel.
// Cross-block h exchange: sentinel protocol, relaxed agent scope (r4-proven
// correctness under any placement). r7 change: poll in 16B chunks (4 MALL
// transactions/thread/round instead of 16) — S was fabric request-rate
// bound, not latency bound.
__global__ __launch_bounds__(256, 1) void lstm_rec(
    const float* __restrict__ x,
    const float* __restrict__ Wxi, const float* __restrict__ Wxf,
    const float* __restrict__ Wxo, const float* __restrict__ Wxc,
    const float* __restrict__ Whi, const float* __restrict__ bhi,
    const float* __restrict__ Whf, const float* __restrict__ bhf,
    const float* __restrict__ Who, const float* __restrict__ bho,
    const float* __restrict__ Whc, const float* __restrict__ bhc,
    uint16_t* __restrict__ hbuf)      // [T_STEPS+1][BATCH][HDIM] bf16 (scratch)
{
    __shared__ __align__(16) uint8_t hA[16 * LDA];   // 16.6 KB
    __shared__ __align__(16) uint8_t xA[16 * LDX];   // 3.3 KB
    __shared__ float gbuf[4 * 16 * 33];              // 8.4 KB

    const int tid  = threadIdx.x;
    const int bid  = blockIdx.x;
    const int xcd  = bid & 7;
    const int slot = bid >> 3;
    const int grp  = xcd * 2 + (slot >> 4);
    const int mem  = slot & 15;
    const int b0   = grp * BBLK;
    const int hs   = mem * HS;

    const int wave  = tid >> 6;       // gate: 0=i 1=f 2=o 3=c
    const int lane  = tid & 63;
    const int col16 = lane & 15;
    const int quad  = lane >> 4;

    const float* Wh  = (wave == 0) ? Whi : (wave == 1) ? Whf : (wave == 2) ? Who : Whc;
    const float* Wxp = (wave == 0) ? Wxi : (wave == 1) ? Wxf : (wave == 2) ? Wxo : Wxc;

    // ---- B-fragments (weights) into registers, once (fp32 -> bf16 RNE) ----
    s8v bh[2][16];
#pragma unroll
    for (int nt = 0; nt < 2; ++nt) {
        const float* rowp = Wh + (size_t)(hs + nt * 16 + col16) * HDIM;
#pragma unroll
        for (int kt = 0; kt < 16; ++kt)
            bh[nt][kt] = cvt8(rowp + kt * 32 + quad * 8);
    }
    s8v bx[2][3];
#pragma unroll
    for (int nt = 0; nt < 2; ++nt) {
        const float* rowp = Wxp + (size_t)(hs + nt * 16 + col16) * DIN;
#pragma unroll
        for (int kt = 0; kt < 3; ++kt) {
            s8v v;
#pragma unroll
            for (int j = 0; j < 8; ++j) {
                int k = kt * 32 + quad * 8 + j;
                v[j] = (k < DIN) ? (short)f2bf(rowp[k]) : (short)0;
            }
            bx[nt][kt] = v;
        }
    }

    // ---- pointwise mapping: thread -> (row r, cols c0,c0+1) of 16x32 slice ----
    const int r  = tid >> 4;
    const int c0 = (tid & 15) * 2;
    const float bi0 = bhi[hs + c0], bi1 = bhi[hs + c0 + 1];
    const float bf0 = bhf[hs + c0], bf1 = bhf[hs + c0 + 1];
    const float bo0 = bho[hs + c0], bo1 = bho[hs + c0 + 1];
    const float bc0 = bhc[hs + c0], bc1 = bhc[hs + c0 + 1];
    float C0 = 0.f, C1 = 0.f;

    uint32_t* hbuf32 = (uint32_t*)hbuf;
    const size_t hslot = ((size_t)(b0 + r) * HDIM + hs + c0) >> 1;

    // ---- refill chunk mapping: chunk c = tid + 256q -> row c>>6, 16B col c&63
    const int rrow[4] = { tid >> 6, (tid + 256) >> 6, (tid + 512) >> 6, (tid + 768) >> 6 };
    const int rc8     = tid & 63;

    // ---- x prefetch (fp32 registers) ----
    float xreg[6];
    auto load_x = [&](int t) {
#pragma unroll
        for (int j = 0; j < 6; ++j) {
            int v = tid + j * 256;
            int row = v / 96, k = v % 96;
            xreg[j] = (k < DIN) ? x[(size_t)(t * BATCH + b0 + row) * DIN + k] : 0.f;
        }
    };
    auto store_x = [&]() {
#pragma unroll
        for (int j = 0; j < 6; ++j) {
            int v = tid + j * 256;
            int row = v / 96, k = v % 96;
            *(uint16_t*)(xA + row * LDX + k * 2) = f2bf(xreg[j]);
        }
    };

    // init: h(0)=0 in LDS, stage x(0)
    load_x(0);
    for (int j = tid; j < 16 * LDA / 16; j += 256) {
        s8v z;
#pragma unroll
        for (int q = 0; q < 8; ++q) z[q] = 0;
        ((s8v*)hA)[j] = z;
    }
    store_x();
    __syncthreads();

    for (int t = 0; t < T_STEPS; ++t) {
        // ---- GEMM: pre-activations for this wave's gate, 16 rows x 32 cols ----
        f4v acc0 = {0.f, 0.f, 0.f, 0.f}, acc1 = {0.f, 0.f, 0.f, 0.f};
#pragma unroll
        for (int kt = 0; kt < 16; ++kt) {
            s8v a = *(const s8v*)(hA + col16 * LDA + kt * 64 + quad * 16);
            acc0 = __builtin_amdgcn_mfma_f32_16x16x32_bf16(a, bh[0][kt], acc0, 0, 0, 0);
            acc1 = __builtin_amdgcn_mfma_f32_16x16x32_bf16(a, bh[1][kt], acc1, 0, 0, 0);
        }
#pragma unroll
        for (int kt = 0; kt < 3; ++kt) {
            s8v a = *(const s8v*)(xA + col16 * LDX + kt * 64 + quad * 16);
            acc0 = __builtin_amdgcn_mfma_f32_16x16x32_bf16(a, bx[0][kt], acc0, 0, 0, 0);
            acc1 = __builtin_amdgcn_mfma_f32_16x16x32_bf16(a, bx[1][kt], acc1, 0, 0, 0);
        }
        // C/D layout: col = lane&15, row = quad*4 + reg
#pragma unroll
        for (int rr = 0; rr < 4; ++rr) {
            int b = quad * 4 + rr;
            gbuf[(wave * 16 + b) * 33 + col16]      = acc0[rr];
            gbuf[(wave * 16 + b) * 33 + 16 + col16] = acc1[rr];
        }

        if (t < T_STEPS - 1) load_x(t + 1);  // flies during pointwise + poll

        __syncthreads();

        // ---- pointwise ----
        float pi0 = gbuf[(0 * 16 + r) * 33 + c0] + bi0;
        float pi1 = gbuf[(0 * 16 + r) * 33 + c0 + 1] + bi1;
        float pf0 = gbuf[(1 * 16 + r) * 33 + c0] + bf0;
        float pf1 = gbuf[(1 * 16 + r) * 33 + c0 + 1] + bf1;
        float po0 = gbuf[(2 * 16 + r) * 33 + c0] + bo0;
        float po1 = gbuf[(2 * 16 + r) * 33 + c0 + 1] + bo1;
        float pc0 = gbuf[(3 * 16 + r) * 33 + c0] + bc0;
        float pc1 = gbuf[(3 * 16 + r) * 33 + c0 + 1] + bc1;

        float I0 = sigm(pi0), F0 = sigm(pf0), O0 = sigm(po0), G0 = tanh_f(pc0);
        float I1 = sigm(pi1), F1 = sigm(pf1), O1 = sigm(po1), G1 = tanh_f(pc1);
        C0 = F0 * C0 + I0 * G0;
        C1 = F1 * C1 + I1 * G1;
        float h0 = O0 * tanh_f(C0);
        float h1 = O1 * tanh_f(C1);

        // fire-and-forget agent store (coherence point); no fence, no drain
        uint32_t packed = (uint32_t)f2bf(h0) | ((uint32_t)f2bf(h1) << 16);
        __hip_atomic_store(&hbuf32[(size_t)(t + 1) * (BATCH * HDIM / 2) + hslot],
                           packed, __ATOMIC_RELAXED, __HIP_MEMORY_SCOPE_AGENT);

        if (t == T_STEPS - 1) break;

        // ---- refill h(t+1): sentinel poll, 16B chunks (low request volume) ----
        const uint32_t* src = hbuf32 + (size_t)(t + 1) * (BATCH * HDIM / 2)
                                     + (size_t)b0 * (HDIM / 2);
        const uint32_t* p0 = src + (size_t)rrow[0] * (HDIM / 2) + rc8 * 4;
        const uint32_t* p1 = src + (size_t)rrow[1] * (HDIM / 2) + rc8 * 4;
        const uint32_t* p2 = src + (size_t)rrow[2] * (HDIM / 2) + rc8 * 4;
        const uint32_t* p3 = src + (size_t)rrow[3] * (HDIM / 2) + rc8 * 4;

        u32x4 v0, v1, v2, v3;
        load16_coh(p0, p1, p2, p3, v0, v1, v2, v3);
        int round = 0;
        while (has_sent(v0) | has_sent(v1) | has_sent(v2) | has_sent(v3)) {
            if (round >= 3) __builtin_amdgcn_s_sleep(2);
            if (has_sent(v0)) v0 = load4_coh(p0);
            if (has_sent(v1)) v1 = load4_coh(p1);
            if (has_sent(v2)) v2 = load4_coh(p2);
            if (has_sent(v3)) v3 = load4_coh(p3);
            if (++round > 50000) break;   // never hang
        }
        *(u32x4*)(hA + rrow[0] * LDA + rc8 * 16) = v0;
        *(u32x4*)(hA + rrow[1] * LDA + rc8 * 16) = v1;
        *(u32x4*)(hA + rrow[2] * LDA + rc8 * 16) = v2;
        *(u32x4*)(hA + rrow[3] * LDA + rc8 * 16) = v3;

        store_x();
        __syncthreads();
    }
}

// Readout: out[t,b,:] = h[t+1] @ Wro^T + bro.  MFMA, N padded 33->48. fp32 out.
__global__ __launch_bounds__(256, 1) void lstm_out(
    const uint16_t* __restrict__ hbuf,
    const float* __restrict__ Wro, const float* __restrict__ bro,
    float* __restrict__ out)
{
    __shared__ __align__(16) uint8_t hT[64 * LDA];   // 66.6 KB

    const int tid   = threadIdx.x;
    const int bid   = blockIdx.x;
    const int wave  = tid >> 6;
    const int lane  = tid & 63;
    const int col16 = lane & 15;
    const int quad  = lane >> 4;

    s8v bw[3][16];
    float bias[3];
#pragma unroll
    for (int nt = 0; nt < 3; ++nt) {
        int o = nt * 16 + col16;
        bias[nt] = (o < NOUT) ? bro[o] : 0.f;
#pragma unroll
        for (int kt = 0; kt < 16; ++kt) {
            if (o < NOUT) {
                bw[nt][kt] = cvt8(Wro + (size_t)o * HDIM + kt * 32 + quad * 8);
            } else {
                s8v z;
#pragma unroll
                for (int q = 0; q < 8; ++q) z[q] = 0;
                bw[nt][kt] = z;
            }
        }
    }

    const uint16_t* hsrc = hbuf + (size_t)BATCH * HDIM;  // skip t=0 slot

    for (int sub = 0; sub < 8; ++sub) {
        size_t row0 = (size_t)bid * 512 + (size_t)sub * 64;
#pragma unroll
        for (int j = 0; j < 16; ++j) {
            int v = tid + j * 256;
            int row = v >> 6, c8 = v & 63;
            s8v val = *(const s8v*)(hsrc + (row0 + row) * HDIM + c8 * 8);
            *(s8v*)(hT + row * LDA + c8 * 16) = val;
        }
        __syncthreads();

        f4v acc[3];
#pragma unroll
        for (int nt = 0; nt < 3; ++nt) acc[nt] = (f4v){0.f, 0.f, 0.f, 0.f};
#pragma unroll
        for (int kt = 0; kt < 16; ++kt) {
            s8v a = *(const s8v*)(hT + (wave * 16 + col16) * LDA + kt * 64 + quad * 16);
#pragma unroll
            for (int nt = 0; nt < 3; ++nt)
                acc[nt] = __builtin_amdgcn_mfma_f32_16x16x32_bf16(a, bw[nt][kt], acc[nt], 0, 0, 0);
        }
#pragma unroll
        for (int nt = 0; nt < 3; ++nt) {
            int o = nt * 16 + col16;
            if (o < NOUT) {
#pragma unroll
                for (int rr = 0; rr < 4; ++rr) {
                    size_t rg = row0 + (size_t)wave * 16 + quad * 4 + rr;
                    out[rg * NOUT + o] = acc[nt][rr] + bias[nt];
                }
            }
        }
        __syncthreads();
    }
}

extern "C" void kernel_launch(void* const* d_in, const int* in_sizes, int n_in,
                              void* d_out, int out_size, void* d_ws, size_t ws_size,
                              hipStream_t stream)
{
    const float* x   = (const float*)d_in[0];
    const float* Wxi = (const float*)d_in[1];
    const float* Wxf = (const float*)d_in[2];
    const float* Wxo = (const float*)d_in[3];
    const float* Wxc = (const float*)d_in[4];
    const float* Whi = (const float*)d_in[5];
    const float* bhi = (const float*)d_in[6];
    const float* Whf = (const float*)d_in[7];
    const float* bhf = (const float*)d_in[8];
    const float* Who = (const float*)d_in[9];
    const float* bho = (const float*)d_in[10];
    const float* Whc = (const float*)d_in[11];
    const float* bhc = (const float*)d_in[12];
    const float* Wro = (const float*)d_in[13];
    const float* bro = (const float*)d_in[14];
    float* out = (float*)d_out;

    uint16_t* hbuf = (uint16_t*)d_ws;   // (T+1)*B*H*2 = 134.5 MB

    lstm_init<<<2048, 256, 0, stream>>>((uint32_t*)hbuf);
    lstm_rec<<<256, 256, 0, stream>>>(x, Wxi, Wxf, Wxo, Wxc,
                                      Whi, bhi, Whf, bhf, Who, bho, Whc, bhc,
                                      hbuf);
    lstm_out<<<256, 256, 0, stream>>>(hbuf, Wro, bro, out);
}